// Round 3
// baseline (320.344 us; speedup 1.0000x reference)
//
#include <hip/hip_runtime.h>
#include <hip/hip_bf16.h>
#include <stdint.h>

typedef __attribute__((ext_vector_type(8)))  __bf16 bf16x8;
typedef __attribute__((ext_vector_type(16))) float  floatx16;
typedef unsigned short ushort8 __attribute__((ext_vector_type(8)));

// ---------------------------------------------------------------------------
// f32 -> bf16 RNE (values here are exactly representable: e4m3 grid x pow2)
__device__ __forceinline__ uint16_t f32_to_bf16_rn(float f) {
    uint32_t u = __float_as_uint(f);
    uint32_t r = u + 0x7FFFu + ((u >> 16) & 1u);
    return (uint16_t)(r >> 16);
}

// ---------------------------------------------------------------------------
// MX quant (block=32 along K, e8m0 scale, e4m3 grid, rint) + dequant to bf16,
// both tensors in one launch. One lane = 16 consecutive floats (half a block);
// 2 lanes = one MX block -> SINGLE shfl_xor level (round 0 had a 3-deep serial
// chain with one 16B load per thread: latency-bound). 4 dwordx4 loads issued
// up front per lane give 4 loads in flight; per-element math identical to the
// verified round-0 kernel.
__global__ __launch_bounds__(256) void quant_dq2_kernel(
    const float* __restrict__ x, const float* __restrict__ w,
    uint16_t* __restrict__ dqx, uint16_t* __restrict__ dqw,
    int nxh, int ntoth)
{
    int t = blockIdx.x * blockDim.x + threadIdx.x;
    if (t >= ntoth) return;
    const float* src; uint16_t* dst; int idx;
    if (t < nxh) { src = x; dst = dqx; idx = t; }
    else         { src = w; dst = dqw; idx = t - nxh; }

    const float4* p = (const float4*)src + (size_t)idx * 4;
    float4 v0 = p[0], v1 = p[1], v2 = p[2], v3 = p[3];
    float r[16] = {v0.x, v0.y, v0.z, v0.w, v1.x, v1.y, v1.z, v1.w,
                   v2.x, v2.y, v2.z, v2.w, v3.x, v3.y, v3.z, v3.w};

    float am = 0.0f;
#pragma unroll
    for (int i = 0; i < 16; ++i) am = fmaxf(am, fabsf(r[i]));
    am = fmaxf(am, __shfl_xor(am, 1));   // block amax across the lane pair

    float scale, iscale;
    if (am > 0.0f) {
        // floor(log2(am)) == exponent field - 127 (subnormal -> -127 = ref clip)
        int se = (int)((__float_as_uint(am) >> 23) & 0xFF) - 135;  // -127-8
        se = se < -127 ? -127 : se;
        scale  = __uint_as_float((uint32_t)(se + 127) << 23);
        iscale = __uint_as_float((uint32_t)(127 - se) << 23);
    } else {
        scale = 1.0f; iscale = 1.0f;
    }

    uint16_t o[16];
#pragma unroll
    for (int i = 0; i < 16; ++i) {
        float sv = r[i] * iscale;              // exact (power-of-two)
        float a  = fabsf(sv);
        int e = (int)((__float_as_uint(a) >> 23) & 0xFF) - 127;
        e = e < -6 ? -6 : (e > 8 ? 8 : e);
        float step  = __uint_as_float((uint32_t)(e - 3 + 127) << 23);
        float rstep = __uint_as_float((uint32_t)(3 - e + 127) << 23);
        float q = rintf(a * rstep) * step;     // exact grid snap, RNE like jnp.round
        q = fminf(q, 448.0f);
        float dq = copysignf(q, sv) * scale;   // exact in bf16
        o[i] = f32_to_bf16_rn(dq);
    }
    ushort8 lo, hi;
#pragma unroll
    for (int i = 0; i < 8; ++i) { lo[i] = o[i]; hi[i] = o[i + 8]; }
    ((ushort8*)dst)[idx * 2]     = lo;
    ((ushort8*)dst)[idx * 2 + 1] = hi;
}

// ---------------------------------------------------------------------------
// bf16 GEMM, C[M,N] = A[M,K]*B[N,K]^T + bias[N]. VERBATIM round-0 kernel
// (proven: 180.6 us, absmax 0.03125). 128x128 block tile, BK=64, 256 threads
// (2x2 waves, each wave 2x2 tiles of 32x32x16 MFMA = 64x64).
#define BM 128
#define BN 128
#define BK 64

__global__ __launch_bounds__(256) void gemm_bt_bias(
    const uint16_t* __restrict__ A, const uint16_t* __restrict__ B,
    const float* __restrict__ bias, float* __restrict__ C,
    int M, int N, int K)
{
    __shared__ uint16_t sA[BM * BK];   // [row][k], 128 B per row
    __shared__ uint16_t sB[BN * BK];

    const int tid  = threadIdx.x;
    const int wave = tid >> 6;
    const int lane = tid & 63;

    const int bm = blockIdx.y * BM;
    const int bn = blockIdx.x * BN;

    // staging: per call 8 rows x 128 B; lane l -> LDS row l>>3, slot l&7;
    // source chunk permuted so LDS[r][slot s] holds global chunk s^(r&7).
    const int srow8  = lane >> 3;
    const int schunk = (lane & 7) ^ srow8;
    const int wrow   = wave * 32;

    const uint16_t* Ag = A + (size_t)(bm + wrow + srow8) * K + schunk * 8;
    const uint16_t* Bg = B + (size_t)(bn + wrow + srow8) * K + schunk * 8;

    const int wm  = (wave & 1) * 64;
    const int wn  = (wave >> 1) * 64;
    const int m32 = lane & 31;      // row/col within a 32-tile
    const int h   = lane >> 5;      // k-half: elements [h*8, h*8+8) of K=16
    const int swz = m32 & 7;        // read-side swizzle key (row&7)

    floatx16 acc[2][2];
#pragma unroll
    for (int i = 0; i < 2; ++i)
#pragma unroll
        for (int j = 0; j < 2; ++j)
#pragma unroll
            for (int r = 0; r < 16; ++r) acc[i][j][r] = 0.0f;

    for (int k0 = 0; k0 < K; k0 += BK) {
        __syncthreads();   // protect LDS while prior tile in use
#pragma unroll
        for (int c = 0; c < 4; ++c) {
            __builtin_amdgcn_global_load_lds(
                (const __attribute__((address_space(1))) void*)(Ag + (size_t)c * 8 * K + k0),
                (__attribute__((address_space(3))) void*)(sA + (wrow + c * 8) * BK),
                16, 0, 0);
        }
#pragma unroll
        for (int c = 0; c < 4; ++c) {
            __builtin_amdgcn_global_load_lds(
                (const __attribute__((address_space(1))) void*)(Bg + (size_t)c * 8 * K + k0),
                (__attribute__((address_space(3))) void*)(sB + (wrow + c * 8) * BK),
                16, 0, 0);
        }
        __syncthreads();   // drains vmcnt before LDS reads

#pragma unroll
        for (int kk = 0; kk < 4; ++kk) {        // 4 K=16 steps per BK=64
            const int chunk = kk * 2 + h;       // wanted global 16B chunk
            const int slot  = chunk ^ swz;      // swizzled LDS slot
            bf16x8 a0 = *(const bf16x8*)(sA + (wm      + m32) * BK + slot * 8);
            bf16x8 a1 = *(const bf16x8*)(sA + (wm + 32 + m32) * BK + slot * 8);
            bf16x8 b0 = *(const bf16x8*)(sB + (wn      + m32) * BK + slot * 8);
            bf16x8 b1 = *(const bf16x8*)(sB + (wn + 32 + m32) * BK + slot * 8);
            acc[0][0] = __builtin_amdgcn_mfma_f32_32x32x16_bf16(a0, b0, acc[0][0], 0, 0, 0);
            acc[0][1] = __builtin_amdgcn_mfma_f32_32x32x16_bf16(a0, b1, acc[0][1], 0, 0, 0);
            acc[1][0] = __builtin_amdgcn_mfma_f32_32x32x16_bf16(a1, b0, acc[1][0], 0, 0, 0);
            acc[1][1] = __builtin_amdgcn_mfma_f32_32x32x16_bf16(a1, b1, acc[1][1], 0, 0, 0);
        }
    }

    // epilogue: 32x32 C/D layout col = lane&31, row = (reg&3)+8*(reg>>2)+4*h
    // [measured: learn_hip m74/m101]
#pragma unroll
    for (int j = 0; j < 2; ++j) {
        const int col = bn + wn + j * 32 + m32;
        const float bz = bias[col];
#pragma unroll
        for (int i = 0; i < 2; ++i) {
            const int rbase = bm + wm + i * 32 + 4 * h;
#pragma unroll
            for (int r = 0; r < 16; ++r) {
                const int row = rbase + (r & 3) + 8 * (r >> 2);
                C[(size_t)row * N + col] = acc[i][j][r] + bz;
            }
        }
    }
}

// ---------------------------------------------------------------------------
extern "C" void kernel_launch(void* const* d_in, const int* in_sizes, int n_in,
                              void* d_out, int out_size, void* d_ws, size_t ws_size,
                              hipStream_t stream) {
    const float* x    = (const float*)d_in[0];
    const float* w    = (const float*)d_in[1];
    const float* bias = (const float*)d_in[2];
    float* out = (float*)d_out;

    const int N = in_sizes[2];            // bias length = out features
    const int K = in_sizes[1] / N;        // weight is [N, K]
    const int M = in_sizes[0] / K;        // x is [M, K] flattened

    uint16_t* dqx = (uint16_t*)d_ws;              // [M,K] bf16
    uint16_t* dqw = dqx + (size_t)M * K;          // [N,K] bf16

    const int nxh   = (M * K) / 16;       // 16 floats per lane
    const int ntoth = nxh + (N * K) / 16;
    quant_dq2_kernel<<<(ntoth + 255) / 256, 256, 0, stream>>>(x, w, dqx, dqw, nxh, ntoth);

    dim3 grid(N / BN, M / BM);
    gemm_bt_bias<<<grid, 256, 0, stream>>>(dqx, dqw, bias, out, M, N, K);
}

// Round 4
// 291.503 us; speedup vs baseline: 1.0989x; 1.0989x over previous
//
#include <hip/hip_runtime.h>
#include <hip/hip_bf16.h>
#include <stdint.h>

typedef __attribute__((ext_vector_type(8)))  __bf16 bf16x8;
typedef __attribute__((ext_vector_type(16))) float  floatx16;
typedef unsigned short ushort8 __attribute__((ext_vector_type(8)));

// ---------------------------------------------------------------------------
// f32 -> bf16 RNE (values here are exactly representable: e4m3 grid x pow2)
__device__ __forceinline__ uint16_t f32_to_bf16_rn(float f) {
    uint32_t u = __float_as_uint(f);
    uint32_t r = u + 0x7FFFu + ((u >> 16) & 1u);
    return (uint16_t)(r >> 16);
}

// ---------------------------------------------------------------------------
// MX quant (block=32 along K, e8m0 scale, e4m3 grid, rint) + dequant to bf16.
// UNCHANGED from round 3 (passed, absmax 0.03125).
__global__ __launch_bounds__(256) void quant_dq2_kernel(
    const float* __restrict__ x, const float* __restrict__ w,
    uint16_t* __restrict__ dqx, uint16_t* __restrict__ dqw,
    int nxh, int ntoth)
{
    int t = blockIdx.x * blockDim.x + threadIdx.x;
    if (t >= ntoth) return;
    const float* src; uint16_t* dst; int idx;
    if (t < nxh) { src = x; dst = dqx; idx = t; }
    else         { src = w; dst = dqw; idx = t - nxh; }

    const float4* p = (const float4*)src + (size_t)idx * 4;
    float4 v0 = p[0], v1 = p[1], v2 = p[2], v3 = p[3];
    float r[16] = {v0.x, v0.y, v0.z, v0.w, v1.x, v1.y, v1.z, v1.w,
                   v2.x, v2.y, v2.z, v2.w, v3.x, v3.y, v3.z, v3.w};

    float am = 0.0f;
#pragma unroll
    for (int i = 0; i < 16; ++i) am = fmaxf(am, fabsf(r[i]));
    am = fmaxf(am, __shfl_xor(am, 1));   // block amax across the lane pair

    float scale, iscale;
    if (am > 0.0f) {
        int se = (int)((__float_as_uint(am) >> 23) & 0xFF) - 135;  // -127-8
        se = se < -127 ? -127 : se;
        scale  = __uint_as_float((uint32_t)(se + 127) << 23);
        iscale = __uint_as_float((uint32_t)(127 - se) << 23);
    } else {
        scale = 1.0f; iscale = 1.0f;
    }

    uint16_t o[16];
#pragma unroll
    for (int i = 0; i < 16; ++i) {
        float sv = r[i] * iscale;              // exact (power-of-two)
        float a  = fabsf(sv);
        int e = (int)((__float_as_uint(a) >> 23) & 0xFF) - 127;
        e = e < -6 ? -6 : (e > 8 ? 8 : e);
        float step  = __uint_as_float((uint32_t)(e - 3 + 127) << 23);
        float rstep = __uint_as_float((uint32_t)(3 - e + 127) << 23);
        float q = rintf(a * rstep) * step;     // exact grid snap, RNE
        q = fminf(q, 448.0f);
        float dq = copysignf(q, sv) * scale;   // exact in bf16
        o[i] = f32_to_bf16_rn(dq);
    }
    ushort8 lo, hi;
#pragma unroll
    for (int i = 0; i < 8; ++i) { lo[i] = o[i]; hi[i] = o[i + 8]; }
    ((ushort8*)dst)[idx * 2]     = lo;
    ((ushort8*)dst)[idx * 2 + 1] = hi;
}

// ---------------------------------------------------------------------------
// bf16 GEMM, C[M,N] = A[M,K]*B[N,K]^T + bias[N].
// 256x256 tile, BK=64, 512 threads (8 waves: 2M x 4N, each wave 128x64 via
// 4x2 tiles of 32x32x16 MFMA). Double-buffered LDS (128 KB dynamic),
// prefetch distance = 1 K-tile with COUNTED vmcnt(8) (T4: never drain to 0
// in-loop), raw s_barrier (no implicit vmcnt(0) drain), setprio around MFMA
// clusters (T5). Staging / chunk^(row&7) swizzle / fragment & C/D layouts
// verbatim from the verified 128x128 kernel.
// Race audit: iteration t stages tile t+1 into buf[(t+1)&1], which was last
// read in iteration t-1 and freed by that iteration's end barrier; reads of
// buf[t&1] happen only between the vmcnt-protected top barrier (all waves'
// tile-t loads retired) and the end barrier.
#define BM 256
#define BN 256
#define BK 64

__global__ __launch_bounds__(512, 2) void gemm_bt_bias(
    const uint16_t* __restrict__ A, const uint16_t* __restrict__ B,
    const float* __restrict__ bias, float* __restrict__ C,
    int M, int N, int K)
{
    extern __shared__ uint8_t lds[];
    uint16_t* sA = (uint16_t*)lds;              // 2 buffers x [256][64] bf16
    uint16_t* sB = (uint16_t*)(lds + 65536);    // 2 buffers x [256][64] bf16

    const int tid  = threadIdx.x;
    const int wave = tid >> 6;
    const int lane = tid & 63;

    // XCD-bijective blockIdx swizzle (nwg=256 divisible by 8): each XCD's 32
    // dispatches map to 32 contiguous tile ids (2 full A-panel rows).
    int lin = blockIdx.y * gridDim.x + blockIdx.x;
    const int nwg = gridDim.x * gridDim.y;
    if ((nwg & 7) == 0) {
        const int q = nwg >> 3;
        lin = (lin & 7) * q + (lin >> 3);
    }
    const int bm = (lin / gridDim.x) * BM;
    const int bn = (lin % gridDim.x) * BN;

    // staging: 4 calls per operand per tile; call c covers rows c*64..c*64+63
    // (128 B each). Thread t -> row c*64 + (t>>3), slot t&7; source chunk
    // pre-permuted so LDS[r][slot s] holds global 16B chunk s^(r&7).
    const int srow   = tid >> 3;                       // 0..63
    const int schunk = ((tid & 7) ^ (srow & 7)) * 8;   // elements
    const uint16_t* Ag = A + (size_t)(bm + srow) * K + schunk;
    const uint16_t* Bg = B + (size_t)(bn + srow) * K + schunk;
    const size_t c64K = (size_t)64 * K;
    uint8_t* dA0 = lds + wave * 1024;           // wave-uniform dest bases
    uint8_t* dB0 = lds + 65536 + wave * 1024;

    const int wm  = (wave >> 2) * 128;   // wave's 128x64 output tile
    const int wn  = (wave & 3) * 64;
    const int m32 = lane & 31;           // row/col within a 32-tile
    const int h   = lane >> 5;           // k-half: elements [h*8, h*8+8)
    const int swz = m32 & 7;             // read-side swizzle key (row&7)

    floatx16 acc[4][2];
#pragma unroll
    for (int i = 0; i < 4; ++i)
#pragma unroll
        for (int j = 0; j < 2; ++j)
#pragma unroll
            for (int r = 0; r < 16; ++r) acc[i][j][r] = 0.0f;

    auto stage = [&](int buf, int tk) {
        const size_t k0 = (size_t)tk * BK;
        uint8_t* dA = dA0 + buf * 32768;
        uint8_t* dB = dB0 + buf * 32768;
#pragma unroll
        for (int c = 0; c < 4; ++c)
            __builtin_amdgcn_global_load_lds(
                (const __attribute__((address_space(1))) void*)(Ag + c * c64K + k0),
                (__attribute__((address_space(3))) void*)(dA + c * 8192), 16, 0, 0);
#pragma unroll
        for (int c = 0; c < 4; ++c)
            __builtin_amdgcn_global_load_lds(
                (const __attribute__((address_space(1))) void*)(Bg + c * c64K + k0),
                (__attribute__((address_space(3))) void*)(dB + c * 8192), 16, 0, 0);
    };

    const int NT = K / BK;
    stage(0, 0);                                  // prologue: tile 0 -> buf 0

    for (int t = 0; t < NT; ++t) {
        const int cur = t & 1;
        if (t + 1 < NT) {
            stage(cur ^ 1, t + 1);                // 8 more loads in flight
            asm volatile("s_waitcnt vmcnt(8)" ::: "memory");  // tile t landed
        } else {
            asm volatile("s_waitcnt vmcnt(0)" ::: "memory");
        }
        __builtin_amdgcn_s_barrier();             // buf[cur] valid for all
        __builtin_amdgcn_sched_barrier(0);

        const uint16_t* bufA = sA + cur * 16384;
        const uint16_t* bufB = sB + cur * 16384;

        bf16x8 bB[2][4];
#pragma unroll
        for (int nj = 0; nj < 2; ++nj) {
            const int row = wn + nj * 32 + m32;
#pragma unroll
            for (int ks = 0; ks < 4; ++ks) {
                const int slot = (ks * 2 + h) ^ swz;
                bB[nj][ks] = *(const bf16x8*)(bufB + row * BK + slot * 8);
            }
        }
#pragma unroll
        for (int mi = 0; mi < 4; ++mi) {
            const int row = wm + mi * 32 + m32;
            bf16x8 aA[4];
#pragma unroll
            for (int ks = 0; ks < 4; ++ks) {
                const int slot = (ks * 2 + h) ^ swz;
                aA[ks] = *(const bf16x8*)(bufA + row * BK + slot * 8);
            }
            __builtin_amdgcn_s_setprio(1);
#pragma unroll
            for (int ks = 0; ks < 4; ++ks) {
                acc[mi][0] = __builtin_amdgcn_mfma_f32_32x32x16_bf16(aA[ks], bB[0][ks], acc[mi][0], 0, 0, 0);
                acc[mi][1] = __builtin_amdgcn_mfma_f32_32x32x16_bf16(aA[ks], bB[1][ks], acc[mi][1], 0, 0, 0);
            }
            __builtin_amdgcn_s_setprio(0);
        }
        __builtin_amdgcn_sched_barrier(0);
        __builtin_amdgcn_s_barrier();             // buf[cur] free for restage
    }

    // epilogue: 32x32 C/D layout col = lane&31, row = (reg&3)+8*(reg>>2)+4*h
    // [measured: learn_hip m74/m101]
#pragma unroll
    for (int nj = 0; nj < 2; ++nj) {
        const int col = bn + wn + nj * 32 + m32;
        const float bz = bias[col];
#pragma unroll
        for (int mi = 0; mi < 4; ++mi) {
            const int rbase = bm + wm + mi * 32 + 4 * h;
#pragma unroll
            for (int r = 0; r < 16; ++r) {
                const int row = rbase + (r & 3) + 8 * (r >> 2);
                C[(size_t)row * N + col] = acc[mi][nj][r] + bz;
            }
        }
    }
}

// ---------------------------------------------------------------------------
extern "C" void kernel_launch(void* const* d_in, const int* in_sizes, int n_in,
                              void* d_out, int out_size, void* d_ws, size_t ws_size,
                              hipStream_t stream) {
    const float* x    = (const float*)d_in[0];
    const float* w    = (const float*)d_in[1];
    const float* bias = (const float*)d_in[2];
    float* out = (float*)d_out;

    const int N = in_sizes[2];            // bias length = out features
    const int K = in_sizes[1] / N;        // weight is [N, K]
    const int M = in_sizes[0] / K;        // x is [M, K] flattened

    uint16_t* dqx = (uint16_t*)d_ws;              // [M,K] bf16
    uint16_t* dqw = dqx + (size_t)M * K;          // [N,K] bf16

    const int nxh   = (M * K) / 16;       // 16 floats per lane
    const int ntoth = nxh + (N * K) / 16;
    quant_dq2_kernel<<<(ntoth + 255) / 256, 256, 0, stream>>>(x, w, dqx, dqw, nxh, ntoth);

    // 128 KB dynamic LDS needs the opt-in attribute (host-side state, not a
    // stream op: graph-capture safe; idempotent per call).
    hipFuncSetAttribute((const void*)gemm_bt_bias,
                        hipFuncAttributeMaxDynamicSharedMemorySize, 131072);
    dim3 grid(N / BN, M / BM);
    gemm_bt_bias<<<grid, 512, 131072, stream>>>(dqx, dqw, bias, out, M, N, K);
}

// Round 5
// 273.209 us; speedup vs baseline: 1.1725x; 1.0670x over previous
//
#include <hip/hip_runtime.h>
#include <hip/hip_bf16.h>
#include <stdint.h>

typedef __attribute__((ext_vector_type(8)))  __bf16 bf16x8;
typedef __attribute__((ext_vector_type(4)))  float  floatx4;
typedef unsigned short ushort8 __attribute__((ext_vector_type(8)));

// ---------------------------------------------------------------------------
// f32 -> bf16 RNE (values here are exactly representable: e4m3 grid x pow2)
__device__ __forceinline__ uint16_t f32_to_bf16_rn(float f) {
    uint32_t u = __float_as_uint(f);
    uint32_t r = u + 0x7FFFu + ((u >> 16) & 1u);
    return (uint16_t)(r >> 16);
}

// ---------------------------------------------------------------------------
// MX quant (block=32 along K, e8m0 scale, e4m3 grid, rint) + dequant to bf16.
// UNCHANGED from round 3/4 (passed, absmax 0.03125).
__global__ __launch_bounds__(256) void quant_dq2_kernel(
    const float* __restrict__ x, const float* __restrict__ w,
    uint16_t* __restrict__ dqx, uint16_t* __restrict__ dqw,
    int nxh, int ntoth)
{
    int t = blockIdx.x * blockDim.x + threadIdx.x;
    if (t >= ntoth) return;
    const float* src; uint16_t* dst; int idx;
    if (t < nxh) { src = x; dst = dqx; idx = t; }
    else         { src = w; dst = dqw; idx = t - nxh; }

    const float4* p = (const float4*)src + (size_t)idx * 4;
    float4 v0 = p[0], v1 = p[1], v2 = p[2], v3 = p[3];
    float r[16] = {v0.x, v0.y, v0.z, v0.w, v1.x, v1.y, v1.z, v1.w,
                   v2.x, v2.y, v2.z, v2.w, v3.x, v3.y, v3.z, v3.w};

    float am = 0.0f;
#pragma unroll
    for (int i = 0; i < 16; ++i) am = fmaxf(am, fabsf(r[i]));
    am = fmaxf(am, __shfl_xor(am, 1));   // block amax across the lane pair

    float scale, iscale;
    if (am > 0.0f) {
        int se = (int)((__float_as_uint(am) >> 23) & 0xFF) - 135;  // -127-8
        se = se < -127 ? -127 : se;
        scale  = __uint_as_float((uint32_t)(se + 127) << 23);
        iscale = __uint_as_float((uint32_t)(127 - se) << 23);
    } else {
        scale = 1.0f; iscale = 1.0f;
    }

    uint16_t o[16];
#pragma unroll
    for (int i = 0; i < 16; ++i) {
        float sv = r[i] * iscale;              // exact (power-of-two)
        float a  = fabsf(sv);
        int e = (int)((__float_as_uint(a) >> 23) & 0xFF) - 127;
        e = e < -6 ? -6 : (e > 8 ? 8 : e);
        float step  = __uint_as_float((uint32_t)(e - 3 + 127) << 23);
        float rstep = __uint_as_float((uint32_t)(3 - e + 127) << 23);
        float q = rintf(a * rstep) * step;     // exact grid snap, RNE
        q = fminf(q, 448.0f);
        float dq = copysignf(q, sv) * scale;   // exact in bf16
        o[i] = f32_to_bf16_rn(dq);
    }
    ushort8 lo, hi;
#pragma unroll
    for (int i = 0; i < 8; ++i) { lo[i] = o[i]; hi[i] = o[i + 8]; }
    ((ushort8*)dst)[idx * 2]     = lo;
    ((ushort8*)dst)[idx * 2 + 1] = hi;
}

// ---------------------------------------------------------------------------
// bf16 GEMM, C[M,N] = A[M,K]*B[N,K]^T + bias[N] — 8-phase deep-pipelined
// 256x256 template (m201 lineage). BK=64, 512 threads, 8 waves (2M x 4N);
// wave tile 128x64 split across both panel halves: M rows {w0m..+63} u
// {w0m+128..+191}, N cols {w0n..+31} u {w0n+128..+159}. 16x16x32 MFMA
// (16-row frag reads -> 2-way LDS aliasing = free, vs 4-way at 32x32).
// Per K-tile, 4 quadrant-phases: each {ds_read frags | stage 1 half-tile |
// barrier | lgkmcnt(0) | setprio(1) 16xMFMA setprio(0) | barrier}; counted
// vmcnt(6) once per tile (phase 4), never 0 in main loop.
//
// Race audit (half-tile H staged in phase P targets dead data):
//   P1 stages (t+1).A-h1 into buf^1: tile t-1 reads ended at (t-1)P4 barrier.
//   P2 stages (t+2).A-h0 into buf:   A-h0 last read P1 (drained+barrier).
//   P3 stages (t+2).B-h0 into buf:   B-h0 last read P1.
//   P4 stages (t+2).B-h1 into buf:   B-h1 last read P2.
// vmcnt(6) at P4: in-flight = 14 loads (7 halves); waits oldest 8 = all of
// tile t+1; leaves tile t+2's 3 staged halves (6 loads) in flight.
#define BM 256
#define BN 256
#define BK 64

#define MM1(MH,NH,MI,NJ,KS,BF) \
    acc[MH][NH][MI][NJ] = __builtin_amdgcn_mfma_f32_16x16x32_bf16( \
        aF[MI][KS], BF[NJ][KS], acc[MH][NH][MI][NJ], 0, 0, 0)
#define MMA_Q(MH,NH,BF) do { \
    __builtin_amdgcn_s_setprio(1); \
    MM1(MH,NH,0,0,0,BF); MM1(MH,NH,1,0,0,BF); MM1(MH,NH,2,0,0,BF); MM1(MH,NH,3,0,0,BF); \
    MM1(MH,NH,0,1,0,BF); MM1(MH,NH,1,1,0,BF); MM1(MH,NH,2,1,0,BF); MM1(MH,NH,3,1,0,BF); \
    MM1(MH,NH,0,0,1,BF); MM1(MH,NH,1,0,1,BF); MM1(MH,NH,2,0,1,BF); MM1(MH,NH,3,0,1,BF); \
    MM1(MH,NH,0,1,1,BF); MM1(MH,NH,1,1,1,BF); MM1(MH,NH,2,1,1,BF); MM1(MH,NH,3,1,1,BF); \
    __builtin_amdgcn_s_setprio(0); } while (0)

__global__ __launch_bounds__(512, 2) void gemm_bt_bias(
    const uint16_t* __restrict__ A, const uint16_t* __restrict__ B,
    const float* __restrict__ bias, float* __restrict__ C,
    int M, int N, int K)
{
    extern __shared__ uint8_t lds[];   // buf b: A at b*65536, B at +32768

    const int tid  = threadIdx.x;
    const int wave = tid >> 6;
    const int lane = tid & 63;

    // XCD-bijective blockIdx swizzle (nwg = 256, divisible by 8)
    int lin = blockIdx.y * gridDim.x + blockIdx.x;
    const int nwg = gridDim.x * gridDim.y;
    if ((nwg & 7) == 0) { const int q = nwg >> 3; lin = (lin & 7) * q + (lin >> 3); }
    const int bm = (lin / gridDim.x) * BM;
    const int bn = (lin % gridDim.x) * BN;

    // staging: thread t -> panel row (t>>3) (+64 for 2nd round), slot t&7;
    // LDS[r][slot s] holds global 16B chunk s^(r&7) (row&7 == srow&7: halves
    // and rounds shift rows by multiples of 64).
    const int srow   = tid >> 3;
    const int schunk = (tid & 7) ^ (srow & 7);
    const uint16_t* Asrc = A + (size_t)(bm + srow) * K + schunk * 8;
    const uint16_t* Bsrc = B + (size_t)(bn + srow) * K + schunk * 8;
    const size_t rowK = (size_t)64 * K;
    const uint32_t dwave = wave * 1024;

    auto stage = [&](int buf, int tk, int op, int h) {
        const uint16_t* s = (op ? Bsrc : Asrc) + (size_t)tk * BK + (size_t)(2 * h) * rowK;
        uint8_t* d = lds + buf * 65536 + op * 32768 + h * 16384 + dwave;
        __builtin_amdgcn_global_load_lds(
            (const __attribute__((address_space(1))) void*)(s),
            (__attribute__((address_space(3))) void*)(d), 16, 0, 0);
        __builtin_amdgcn_global_load_lds(
            (const __attribute__((address_space(1))) void*)(s + rowK),
            (__attribute__((address_space(3))) void*)(d + 8192), 16, 0, 0);
    };

    const int g   = lane >> 4;        // k-chunk group (8 elems each)
    const int r16 = lane & 15;        // row within a 16-tile
    const int swz = lane & 7;         // row&7 (rows = mult-of-16 + r16)
    const int w0m = (wave >> 2) * 64;
    const int w0n = (wave & 3) * 32;

    auto frag = [&](const uint8_t* panel, int row, int ks) -> bf16x8 {
        const int slot = (ks * 4 + g) ^ swz;
        return *(const bf16x8*)(panel + row * 128 + slot * 16);
    };

    floatx4 acc[2][2][4][2];          // [mhalf][nhalf][mi][nj]
#pragma unroll
    for (int a0 = 0; a0 < 2; ++a0)
#pragma unroll
        for (int a1 = 0; a1 < 2; ++a1)
#pragma unroll
            for (int a2 = 0; a2 < 4; ++a2)
#pragma unroll
                for (int a3 = 0; a3 < 2; ++a3)
#pragma unroll
                    for (int a4 = 0; a4 < 4; ++a4) acc[a0][a1][a2][a3][a4] = 0.0f;

    bf16x8 aF[4][2], bF0[2][2], bF1[2][2];

    const int NT = K / BK;
    // prologue: tile0 all 4 halves + tile1 first 3 (consumption order)
    stage(0, 0, 0, 0); stage(0, 0, 1, 0); stage(0, 0, 1, 1); stage(0, 0, 0, 1);
    stage(1, 1, 0, 0); stage(1, 1, 1, 0); stage(1, 1, 1, 1);
    asm volatile("s_waitcnt vmcnt(6)" ::: "memory");
    __builtin_amdgcn_s_barrier();

    for (int t = 0; t < NT; ++t) {
        const int cur = t & 1, nxt = cur ^ 1;
        const uint8_t* bA = lds + cur * 65536;
        const uint8_t* bB = bA + 32768;

        // ---- P1: quadrant (m0,n0); stage (t+1).A-h1 ----
#pragma unroll
        for (int mi = 0; mi < 4; ++mi) {
            aF[mi][0] = frag(bA, w0m + mi * 16 + r16, 0);
            aF[mi][1] = frag(bA, w0m + mi * 16 + r16, 1);
        }
#pragma unroll
        for (int nj = 0; nj < 2; ++nj) {
            bF0[nj][0] = frag(bB, w0n + nj * 16 + r16, 0);
            bF0[nj][1] = frag(bB, w0n + nj * 16 + r16, 1);
        }
        if (t + 1 < NT) stage(nxt, t + 1, 0, 1);
        __builtin_amdgcn_sched_barrier(0);
        __builtin_amdgcn_s_barrier();
        asm volatile("s_waitcnt lgkmcnt(0)" ::: "memory");
        __builtin_amdgcn_sched_barrier(0);
        MMA_Q(0, 0, bF0);
        __builtin_amdgcn_sched_barrier(0);
        __builtin_amdgcn_s_barrier();

        // ---- P2: quadrant (m0,n1); stage (t+2).A-h0 ----
#pragma unroll
        for (int nj = 0; nj < 2; ++nj) {
            bF1[nj][0] = frag(bB, w0n + 128 + nj * 16 + r16, 0);
            bF1[nj][1] = frag(bB, w0n + 128 + nj * 16 + r16, 1);
        }
        if (t + 2 < NT) stage(cur, t + 2, 0, 0);
        __builtin_amdgcn_sched_barrier(0);
        __builtin_amdgcn_s_barrier();
        asm volatile("s_waitcnt lgkmcnt(0)" ::: "memory");
        __builtin_amdgcn_sched_barrier(0);
        MMA_Q(0, 1, bF1);
        __builtin_amdgcn_sched_barrier(0);
        __builtin_amdgcn_s_barrier();

        // ---- P3: quadrant (m1,n1); stage (t+2).B-h0 ----
#pragma unroll
        for (int mi = 0; mi < 4; ++mi) {
            aF[mi][0] = frag(bA, w0m + 128 + mi * 16 + r16, 0);
            aF[mi][1] = frag(bA, w0m + 128 + mi * 16 + r16, 1);
        }
        if (t + 2 < NT) stage(cur, t + 2, 1, 0);
        __builtin_amdgcn_sched_barrier(0);
        __builtin_amdgcn_s_barrier();
        asm volatile("s_waitcnt lgkmcnt(0)" ::: "memory");
        __builtin_amdgcn_sched_barrier(0);
        MMA_Q(1, 1, bF1);
        __builtin_amdgcn_sched_barrier(0);
        __builtin_amdgcn_s_barrier();

        // ---- P4: quadrant (m1,n0) (frags all in regs); stage (t+2).B-h1 ----
        if (t + 2 < NT) stage(cur, t + 2, 1, 1);
        __builtin_amdgcn_sched_barrier(0);
        __builtin_amdgcn_s_barrier();
        MMA_Q(1, 0, bF0);
        __builtin_amdgcn_sched_barrier(0);
        if (t < NT - 2) asm volatile("s_waitcnt vmcnt(6)" ::: "memory");
        else            asm volatile("s_waitcnt vmcnt(0)" ::: "memory");
        __builtin_amdgcn_s_barrier();
    }

    // epilogue: 16x16 C/D layout col = lane&15, row = (lane>>4)*4 + reg
    // [measured: learn_hip m89/m91]
#pragma unroll
    for (int mh = 0; mh < 2; ++mh)
#pragma unroll
        for (int nh = 0; nh < 2; ++nh)
#pragma unroll
            for (int nj = 0; nj < 2; ++nj) {
                const int col = bn + w0n + nh * 128 + nj * 16 + r16;
                const float bz = bias[col];
#pragma unroll
                for (int mi = 0; mi < 4; ++mi) {
                    const int rowb = bm + w0m + mh * 128 + mi * 16 + g * 4;
#pragma unroll
                    for (int rr = 0; rr < 4; ++rr)
                        C[(size_t)(rowb + rr) * N + col] = acc[mh][nh][mi][nj][rr] + bz;
                }
            }
}

// ---------------------------------------------------------------------------
extern "C" void kernel_launch(void* const* d_in, const int* in_sizes, int n_in,
                              void* d_out, int out_size, void* d_ws, size_t ws_size,
                              hipStream_t stream) {
    const float* x    = (const float*)d_in[0];
    const float* w    = (const float*)d_in[1];
    const float* bias = (const float*)d_in[2];
    float* out = (float*)d_out;

    const int N = in_sizes[2];            // bias length = out features
    const int K = in_sizes[1] / N;        // weight is [N, K]
    const int M = in_sizes[0] / K;        // x is [M, K] flattened

    uint16_t* dqx = (uint16_t*)d_ws;              // [M,K] bf16
    uint16_t* dqw = dqx + (size_t)M * K;          // [N,K] bf16

    const int nxh   = (M * K) / 16;       // 16 floats per lane
    const int ntoth = nxh + (N * K) / 16;
    quant_dq2_kernel<<<(ntoth + 255) / 256, 256, 0, stream>>>(x, w, dqx, dqw, nxh, ntoth);

    // 128 KB dynamic LDS opt-in (host-side state; graph-capture safe).
    hipFuncSetAttribute((const void*)gemm_bt_bias,
                        hipFuncAttributeMaxDynamicSharedMemorySize, 131072);
    dim3 grid(N / BN, M / BM);
    gemm_bt_bias<<<grid, 512, 131072, stream>>>(dqx, dqw, bias, out, M, N, K);
}